// Round 9
// baseline (92.218 us; speedup 1.0000x reference)
//
#include <hip/hip_runtime.h>

typedef _Float16 f16;
typedef _Float16 f16x2 __attribute__((ext_vector_type(2)));
typedef _Float16 f16x4 __attribute__((ext_vector_type(4)));
typedef _Float16 f16x8 __attribute__((ext_vector_type(8)));
typedef float    f32x4 __attribute__((ext_vector_type(4)));
typedef unsigned int u32;
typedef u32      u32x2 __attribute__((ext_vector_type(2)));
typedef u32      u32x4 __attribute__((ext_vector_type(4)));

#define MFMA32(a, b, c) __builtin_amdgcn_mfma_f32_16x16x32_f16((a), (b), (c), 0, 0, 0)
// NOTE: legacy K=16 intrinsic has NO underscore before f16 on gfx950
#define MFMA16(a, b, c) __builtin_amdgcn_mfma_f32_16x16x16f16((a), (b), (c), 0, 0, 0)

#define TILES 8   // batch-tiles (of 16) per block; grid = 8192/TILES

__device__ __forceinline__ float leaky(float x) {
    return fmaf(0.4f, __builtin_fabsf(x), 0.6f * x);
}
__device__ __forceinline__ u32 pkrtz(float a, float b) {
    return __builtin_bit_cast(u32, __builtin_amdgcn_cvt_pkrtz(a, b));
}
// leaky(x) == max(x, 0.2x): x>=0 -> x exact; x<0 -> 0.2x (f16 rne). 3 ops/pair.
__device__ __forceinline__ u32 lk_pk2(float a, float b) {
    f16x2 v = __builtin_bit_cast(f16x2, __builtin_amdgcn_cvt_pkrtz(a, b));
    f16x2 s = v * (f16x2){(f16)0.2f, (f16)0.2f};
    f16x2 r = __builtin_elementwise_max(v, s);
    return __builtin_bit_cast(u32, r);
}
__device__ __forceinline__ f16x4 lk_pk4(const f32x4 z) {
    return __builtin_bit_cast(f16x4, (u32x2){ lk_pk2(z[0], z[1]), lk_pk2(z[2], z[3]) });
}
__device__ __forceinline__ f16x4 pk4(const f32x4 z) {
    return __builtin_bit_cast(f16x4, (u32x2){ pkrtz(z[0], z[1]), pkrtz(z[2], z[3]) });
}
__device__ __forceinline__ void st_lk4(void* p, const f32x4 z) {
    *(u32x2*)p = (u32x2){ lk_pk2(z[0], z[1]), lk_pk2(z[2], z[3]) };
}

// ---------------------------------------------------------------------------
// Prepack: f16 MFMA fragments in d_ws (unchanged).
// ---------------------------------------------------------------------------
__global__ void disc_prepack(const float* __restrict__ Wp1, const float* __restrict__ Wp2,
                             const float* __restrict__ Wn1, const float* __restrict__ Wn2,
                             const float* __restrict__ Wl1, const float* __restrict__ Wl2,
                             f16* __restrict__ ws)
{
    int idx = blockIdx.x * 256 + threadIdx.x;
    if (idx >= 84 * 512 + 24 * 256) return;
    float v = 0.0f;
    if (idx < 84 * 512) {
        int f = idx >> 9, r = idx & 511;
        int lane = r >> 3, e = r & 7;
        int m15 = lane & 15, h = lane >> 4;
        if (f < 64) {
            int mt4 = f >> 4, ks4 = f & 15;
            int k = ks4 * 32 + h * 8 + e;
            v = Wl1[k * 64 + mt4 * 16 + m15];
        } else if (f < 72) {
            int q = f - 64, c = q >> 2, mt = q & 3;
            const float* W1 = c ? Wn1 : Wp1;
            v = (lane < 16) ? W1[e * 64 + mt * 16 + m15] : 0.0f;
        } else if (f < 80) {
            int q = f - 72, c = q >> 2, nt2 = (q >> 1) & 1, ks2 = q & 1;
            const float* W2 = c ? Wn2 : Wp2;
            int k = ks2 * 32 + h * 8 + e;
            v = W2[k * 32 + nt2 * 16 + m15];
        } else {
            int q = f - 80, ms5 = q >> 1, ks5 = q & 1;
            int k = ks5 * 32 + h * 8 + e;
            v = Wl2[k * 32 + ms5 * 16 + m15];
        }
    } else {
        int r2 = idx - 84 * 512;
        int f2 = r2 >> 8, rr = r2 & 255;
        int lane = rr >> 2, e = rr & 3;
        int m15 = lane & 15, h = lane >> 4;
        if (f2 < 16) {
            int c = f2 >> 3, kb = (f2 >> 1) & 3, nt = f2 & 1;
            const float* W2 = c ? Wn2 : Wp2;
            v = W2[(kb * 16 + h * 4 + e) * 32 + nt * 16 + m15];
        } else {
            int q = f2 - 16, kb = q >> 1, nt = q & 1;
            v = Wl2[(kb * 16 + h * 4 + e) * 32 + nt * 16 + m15];
        }
    }
    ws[idx] = (f16)v;
}

// ---------------------------------------------------------------------------
// R22: R17 shell + Phase-C VMEM attack.
//   R13-R21 POST-MORTEM: every clean parallelism/ILP variant = 53.6-54.7us;
//   wave lifetime ~41us INDEPENDENT of per-wave work (R16 8-tile vs R20
//   4-tile waves); VALU busy-time fell 24->16us with dur constant. The
//   untouched fixed cost: Phase C pulls 32KB/tile-channel of Wl1 frags
//   through a thrashing L1 (both waves' halves = 64KB > 32KB L1) -> every
//   load is an L2 round-trip INSIDE the 8-step acc dependency chain
//   (~1600cy exposed per channel per tile; 512MB/dispatch of repeat reads).
//   Fixes:
//   (1) k8 0..3 of this wave's Wl1 half RESIDENT in 16 f16x8 VGPRs,
//       loaded once per block (amortized over 8 tiles) -> half of Phase C
//       is pure-register MFMA.
//   (2) Dual acc chains: resident-half chain never waits on VMEM; vmem-half
//       interleaved so loads hide under resident-half compute. Sum at end.
//   (3) Phase B back to unroll 1 (2 streams) to fund the 64 resident regs.
// LDS: 2 x 10240 wave areas + 2 x 4096 dbuf xchg = 28672 (as R17).
// ---------------------------------------------------------------------------
__global__ __launch_bounds__(128, 2) void disc_main(
    const float* __restrict__ adj,
    const float* __restrict__ bp1, const float* __restrict__ bp2,
    const float* __restrict__ bn1, const float* __restrict__ bn2,
    const float* __restrict__ bl1, const float* __restrict__ bl2,
    const float* __restrict__ bl3, const float* __restrict__ Wl3,
    const f16* __restrict__ ws, float* __restrict__ out)
{
    extern __shared__ char smem[];
    const int tid  = threadIdx.x;
    const int lane = tid & 63;
    const int wid  = tid >> 6;      // == channel c this wave owns
    const int h    = lane >> 4;
    const int m15  = lane & 15;
    const int i7   = lane & 7;
    const int r8   = m15 >> 3;

    const f16x8* wsf = (const f16x8*)ws;
    const f16x4* wsq = (const f16x4*)(ws + 84 * 512);   // 16x16x16 B-frags
    const int c = wid;

    // ---- this wave's channel weights/biases (loaded ONCE for all tiles) ---
    const f16x8* w1p = wsf + (64 + c * 4) * 64 + lane;
    f16x8 w1t0 = w1p[0], w1t1 = w1p[64], w1t2 = w1p[128], w1t3 = w1p[192];
    const f16x4* w2p = wsq + (c * 8) * 64 + lane;
    f16x4 w2k00 = w2p[0],   w2k01 = w2p[64];    // kb=0, nt=0/1
    f16x4 w2k10 = w2p[128], w2k11 = w2p[192];   // kb=1
    f16x4 w2k20 = w2p[256], w2k21 = w2p[320];   // kb=2
    f16x4 w2k30 = w2p[384], w2k31 = w2p[448];   // kb=3
    const f32x4* b1p = (const f32x4*)(c ? bn1 : bp1);
    f32x4 b10 = b1p[h], b11 = b1p[4 + h], b12 = b1p[8 + h], b13 = b1p[12 + h];
    const f32x4* b2p = (const f32x4*)(c ? bn2 : bp2);
    f32x4 b20 = b2p[h], b21 = b2p[4 + h];
    f32x4 bl1v0 = ((const f32x4*)bl1)[h],      bl1v1 = ((const f32x4*)bl1)[4 + h];
    f32x4 bl1v2 = ((const f32x4*)bl1)[8 + h],  bl1v3 = ((const f32x4*)bl1)[12 + h];

    // ---- RESIDENT Phase-C weights: k8 = 0..3 of this wave's Wl1 half ----
    // 16 f16x8 = 64 VGPRs, loaded once, reused by all 8 tiles.
    f16x8 wr[16];
    #pragma unroll
    for (int k8 = 0; k8 < 4; ++k8) {
        const f16x8* wl = wsf + (c * 8 + k8) * 64 + lane;
        wr[4 * k8 + 0] = wl[0];
        wr[4 * k8 + 1] = wl[1024];
        wr[4 * k8 + 2] = wl[2048];
        wr[4 * k8 + 3] = wl[3072];
    }

    // ---- tail weights (wave0 only), hoisted out of the tile loop ----
    f16x4 l200, l201, l210, l211, l220, l221, l230, l231;
    float c0 = 0.0f, c1 = 0.0f, w30 = 0.0f, w31 = 0.0f, bl3s = 0.0f;
    if (wid == 0) {
        const f16x4* wl2p = wsq + 16 * 64 + lane;
        l200 = wl2p[0];   l201 = wl2p[64];
        l210 = wl2p[128]; l211 = wl2p[192];
        l220 = wl2p[256]; l221 = wl2p[320];
        l230 = wl2p[384]; l231 = wl2p[448];
        c0 = bl2[m15]; c1 = bl2[m15 + 16];
        w30 = Wl3[m15]; w31 = Wl3[m15 + 16];
        bl3s = bl3[0];
    }

    char* wbase = smem + wid * 10240;
    char* Albuf = wbase;              // 2048 B
    char* xbuf  = wbase + 2048;       // 8192 B (8 swizzled 1KB frags)

    const int rxor = ((m15 >> 1) & 3) << 4;
    const bool bsel = ((h >> 1) == r8);    // s3 B-frag block-diag gate
    const int  hlow = h & 1;               // s3 B-frag row-half select
    f32x4 zero4 = {0.0f, 0.0f, 0.0f, 0.0f};
    f16x4 zf4 = {};

    long b0 = (long)blockIdx.x * (16 * TILES);

    // ---- prefetch tile 0's raw adj rows into registers ----
    f32x4 c00, c01, c10, c11;
    {
        const f32x4* rp0 = (const f32x4*)(adj + (b0 + (lane >> 3)) * 128 + c * 64 + (lane & 7) * 8);
        c00 = rp0[0]; c01 = rp0[1];
        const int rid1 = 64 + lane;
        const f32x4* rp1 = (const f32x4*)(adj + (b0 + (rid1 >> 3)) * 128 + c * 64 + (rid1 & 7) * 8);
        c10 = rp1[0]; c11 = rp1[1];
    }

    #pragma unroll 1
    for (int it = 0; it < TILES; ++it, b0 += 16) {
        // ---- Phase A: normalize prefetched rows, stage to Albuf ----
        {
            float s = ((c00[0] + c00[1]) + (c00[2] + c00[3])) + ((c01[0] + c01[1]) + (c01[2] + c01[3]));
            float rv = (s > 0.0f) ? __builtin_amdgcn_rcpf(s) : 0.0f;
            u32x4 row = { pkrtz(c00[0] * rv, c00[1] * rv), pkrtz(c00[2] * rv, c00[3] * rv),
                          pkrtz(c01[0] * rv, c01[1] * rv), pkrtz(c01[2] * rv, c01[3] * rv) };
            *(u32x4*)(Albuf + lane * 16) = row;
        }
        {
            float s = ((c10[0] + c10[1]) + (c10[2] + c10[3])) + ((c11[0] + c11[1]) + (c11[2] + c11[3]));
            float rv = (s > 0.0f) ? __builtin_amdgcn_rcpf(s) : 0.0f;
            u32x4 row = { pkrtz(c10[0] * rv, c10[1] * rv), pkrtz(c10[2] * rv, c10[3] * rv),
                          pkrtz(c11[0] * rv, c11[1] * rv), pkrtz(c11[2] * rv, c11[3] * rv) };
            *(u32x4*)(Albuf + (64 + lane) * 16) = row;
        }

        // ---- prefetch next tile's raw rows (hides HBM under B/C compute) --
        f32x4 n00, n01, n10, n11;
        const bool more = (it + 1 < TILES);
        if (more) {
            const f32x4* rp0 = (const f32x4*)(adj + (b0 + 16 + (lane >> 3)) * 128 + c * 64 + (lane & 7) * 8);
            n00 = rp0[0]; n01 = rp0[1];
            const int rid1 = 64 + lane;
            const f32x4* rp1 = (const f32x4*)(adj + (b0 + 16 + (rid1 >> 3)) * 128 + c * 64 + (rid1 & 7) * 8);
            n10 = rp1[0]; n11 = rp1[1];
        }

        // ---- Phase B: fused GCN, TWO independent t-streams ----
        #pragma unroll 1
        for (int tp = 0; tp < 4; ++tp) {
            const int ta = tp, tb = tp + 4;
            f16x8 arow_a = *(const f16x8*)(Albuf + (((2 * ta + r8) * 8 + i7) << 4));
            f16x8 arow_b = *(const f16x8*)(Albuf + (((2 * tb + r8) * 8 + i7) << 4));

            // s1 both: z^T = W1^T @ A^T + b1 (16x16x32, K=8 pad)
            f32x4 z0a = MFMA32(w1t0, arow_a, b10);
            f32x4 z1a = MFMA32(w1t1, arow_a, b11);
            f32x4 z2a = MFMA32(w1t2, arow_a, b12);
            f32x4 z3a = MFMA32(w1t3, arow_a, b13);
            f32x4 z0b = MFMA32(w1t0, arow_b, b10);
            f32x4 z1b = MFMA32(w1t1, arow_b, b11);
            f32x4 z2b = MFMA32(w1t2, arow_b, b12);
            f32x4 z3b = MFMA32(w1t3, arow_b, b13);

            // s1 -> s2: register pack+leaky (packed f16 math)
            f16x4 xa0 = lk_pk4(z0a), xa1 = lk_pk4(z1a), xa2 = lk_pk4(z2a), xa3 = lk_pk4(z3a);
            f16x4 xb0 = lk_pk4(z0b), xb1 = lk_pk4(z1b), xb2 = lk_pk4(z2b), xb3 = lk_pk4(z3b);

            // s2 both: y_nt = sum_kb x1 @ W2 (4-chain of 16x16x16, 4 indep chains)
            f32x4 y0a = MFMA16(xa0, w2k00, zero4);
            f32x4 y1a = MFMA16(xa0, w2k01, zero4);
            f32x4 y0b = MFMA16(xb0, w2k00, zero4);
            f32x4 y1b = MFMA16(xb0, w2k01, zero4);
            y0a = MFMA16(xa1, w2k10, y0a);
            y1a = MFMA16(xa1, w2k11, y1a);
            y0b = MFMA16(xb1, w2k10, y0b);
            y1b = MFMA16(xb1, w2k11, y1b);
            y0a = MFMA16(xa2, w2k20, y0a);
            y1a = MFMA16(xa2, w2k21, y1a);
            y0b = MFMA16(xb2, w2k20, y0b);
            y1b = MFMA16(xb2, w2k21, y1b);
            y0a = MFMA16(xa3, w2k30, y0a);
            y1a = MFMA16(xa3, w2k31, y1a);
            y0b = MFMA16(xb3, w2k30, y0b);
            y1b = MFMA16(xb3, w2k31, y1b);

            // s2 -> s3: register pkrtz; B-frag from arow select (block-diag)
            f16x4 pa0 = pk4(y0a), pa1 = pk4(y1a);
            f16x4 pb0 = pk4(y0b), pb1 = pk4(y1b);
            u32x4 ara = __builtin_bit_cast(u32x4, arow_a);
            u32x4 arb = __builtin_bit_cast(u32x4, arow_b);
            f16x4 halfa = __builtin_bit_cast(f16x4,
                hlow ? (u32x2){ara[2], ara[3]} : (u32x2){ara[0], ara[1]});
            f16x4 halfb = __builtin_bit_cast(f16x4,
                hlow ? (u32x2){arb[2], arb[3]} : (u32x2){arb[0], arb[1]});
            f16x4 bfra = bsel ? halfa : zf4;
            f16x4 bfrb = bsel ? halfb : zf4;

            // s3 both: x2^T = y^T @ BD_A^T + b2 (16x16x16, K=16 exact)
            f32x4 x2aa = MFMA16(pa0, bfra, b20);
            f32x4 x2ba = MFMA16(pa1, bfra, b21);
            f32x4 x2ab = MFMA16(pb0, bfrb, b20);
            f32x4 x2bb = MFMA16(pb1, bfrb, b21);

            // leaky+pack + swizzled xbuf writes; slot = i7, n = 2t+r8
            const int lga = h >> 1;
            const int lgb = (lga + 2) & 3;
            char* fb = xbuf + (i7 << 10);
            {
                int wx = ((ta & 3) ^ i7) << 4;
                int basew = ((2 * ta + r8) << 6) + ((h & 1) << 3);
                st_lk4(fb + ((basew + lga * 16) ^ wx), x2aa);
                st_lk4(fb + ((basew + lgb * 16) ^ wx), x2ba);
            }
            {
                int wx = ((tb & 3) ^ i7) << 4;
                int basew = ((2 * tb + r8) << 6) + ((h & 1) << 3);
                st_lk4(fb + ((basew + lga * 16) ^ wx), x2ab);
                st_lk4(fb + ((basew + lgb * 16) ^ wx), x2bb);
            }
        }

        // ---- Phase C: h1 partial += Wl1^T[k-half c] @ x^T (K=256) ----
        // Dual chains: k8 0..3 from RESIDENT regs (chain a4x, never waits on
        // VMEM); k8 4..7 from global (chain b4x), loads interleaved so they
        // issue early and land under the resident-chain MFMAs.
        f32x4 a40 = wid ? zero4 : bl1v0;
        f32x4 a41 = wid ? zero4 : bl1v1;
        f32x4 a42 = wid ? zero4 : bl1v2;
        f32x4 a43 = wid ? zero4 : bl1v3;
        f32x4 b40 = zero4, b41 = zero4, b42 = zero4, b43 = zero4;
        __builtin_amdgcn_s_setprio(1);
        #pragma unroll
        for (int j = 0; j < 4; ++j) {
            const int kv = 4 + j;
            // vmem-half loads first in program order (issue early)
            const f16x8* wl = wsf + (c * 8 + kv) * 64 + lane;
            f16x8 wv0 = wl[0], wv1 = wl[1024], wv2 = wl[2048], wv3 = wl[3072];
            int xrv = rxor ^ (kv << 4);
            f16x8 xfv = *(const f16x8*)(xbuf + (kv << 10) + ((m15 * 64 + h * 16) ^ xrv));
            // resident-half compute (no VMEM dependence) overlaps the loads
            int xr = rxor ^ (j << 4);
            f16x8 xf = *(const f16x8*)(xbuf + (j << 10) + ((m15 * 64 + h * 16) ^ xr));
            a40 = MFMA32(wr[4 * j + 0], xf, a40);
            a41 = MFMA32(wr[4 * j + 1], xf, a41);
            a42 = MFMA32(wr[4 * j + 2], xf, a42);
            a43 = MFMA32(wr[4 * j + 3], xf, a43);
            // vmem-half compute
            b40 = MFMA32(wv0, xfv, b40);
            b41 = MFMA32(wv1, xfv, b41);
            b42 = MFMA32(wv2, xfv, b42);
            b43 = MFMA32(wv3, xfv, b43);
        }
        __builtin_amdgcn_s_setprio(0);
        a40 += b40; a41 += b41; a42 += b42; a43 += b43;

        // ---- cross-wave partial exchange: double-buffered xchg, ONE barrier
        char* xc = smem + 20480 + ((it & 1) << 12);
        if (wid == 1) {
            *(f32x4*)(xc +    0 + lane * 16) = a40;
            *(f32x4*)(xc + 1024 + lane * 16) = a41;
            *(f32x4*)(xc + 2048 + lane * 16) = a42;
            *(f32x4*)(xc + 3072 + lane * 16) = a43;
        }
        __syncthreads();   // wave1 proceeds into tile t+1 (other xchg buffer)

        if (wid == 0) {
            a40 += *(const f32x4*)(xc +    0 + lane * 16);
            a41 += *(const f32x4*)(xc + 1024 + lane * 16);
            a42 += *(const f32x4*)(xc + 2048 + lane * 16);
            a43 += *(const f32x4*)(xc + 3072 + lane * 16);

            // ---- Phase D: register pack+leaky of h1 (A-frags for E) ----
            f16x4 pd0 = lk_pk4(a40), pd1 = lk_pk4(a41);
            f16x4 pd2 = lk_pk4(a42), pd3 = lk_pk4(a43);

            // ---- Phase E: h2 = h1 @ Wl2 + bl2 (4-chain 16x16x16 per nt) --
            f32x4 a50 = {c0, c0, c0, c0};
            f32x4 a51 = {c1, c1, c1, c1};
            a50 = MFMA16(pd0, l200, a50);
            a51 = MFMA16(pd0, l201, a51);
            a50 = MFMA16(pd1, l210, a50);
            a51 = MFMA16(pd1, l211, a51);
            a50 = MFMA16(pd2, l220, a50);
            a51 = MFMA16(pd2, l221, a51);
            a50 = MFMA16(pd3, l230, a50);
            a51 = MFMA16(pd3, l231, a51);

            // ---- Phase F: out[b=4h+r] = sum_l2 leaky(h2) Wl3 + bl3 ----
            #pragma unroll
            for (int r = 0; r < 4; ++r) {
                float acc = leaky(a50[r]) * w30 + leaky(a51[r]) * w31;
                acc += __shfl_xor(acc, 1);
                acc += __shfl_xor(acc, 2);
                acc += __shfl_xor(acc, 4);
                acc += __shfl_xor(acc, 8);
                if (m15 == 0) out[b0 + h * 4 + r] = acc + bl3s;
            }
        }

        // ---- rotate prefetched rows ----
        if (more) { c00 = n00; c01 = n01; c10 = n10; c11 = n11; }
    }
}

extern "C" void kernel_launch(void* const* d_in, const int* in_sizes, int n_in,
                              void* d_out, int out_size, void* d_ws, size_t ws_size,
                              hipStream_t stream)
{
    const float* adj  = (const float*)d_in[0];
    const float* Wp1  = (const float*)d_in[1];
    const float* bp1  = (const float*)d_in[2];
    const float* Wp2  = (const float*)d_in[3];
    const float* bp2  = (const float*)d_in[4];
    const float* Wn1  = (const float*)d_in[5];
    const float* bn1  = (const float*)d_in[6];
    const float* Wn2  = (const float*)d_in[7];
    const float* bn2  = (const float*)d_in[8];
    const float* Wl1  = (const float*)d_in[9];
    const float* bl1  = (const float*)d_in[10];
    const float* Wl2  = (const float*)d_in[11];
    const float* bl2  = (const float*)d_in[12];
    const float* Wl3  = (const float*)d_in[13];
    const float* bl3  = (const float*)d_in[14];
    f16* ws = (f16*)d_ws;
    float* out = (float*)d_out;

    // 84*512 + 24*256 = 49152 f16; 192 blocks x 256 threads
    hipLaunchKernelGGL(disc_prepack, dim3(192), dim3(256), 0, stream,
                       Wp1, Wp2, Wn1, Wn2, Wl1, Wl2, ws);

    const int ldsBytes = 28672;  // 2 x 10240 wave areas + 2 x 4096 xchg
    hipFuncSetAttribute(reinterpret_cast<const void*>(disc_main),
                        hipFuncAttributeMaxDynamicSharedMemorySize, ldsBytes);
    hipLaunchKernelGGL(disc_main, dim3(8192 / TILES), dim3(128), ldsBytes, stream,
                       adj, bp1, bp2, bn1, bn2, bl1, bl2, bl3, Wl3, ws, out);
}

// Round 10
// 71.830 us; speedup vs baseline: 1.2838x; 1.2838x over previous
//
#include <hip/hip_runtime.h>

typedef _Float16 f16;
typedef _Float16 f16x2 __attribute__((ext_vector_type(2)));
typedef _Float16 f16x4 __attribute__((ext_vector_type(4)));
typedef _Float16 f16x8 __attribute__((ext_vector_type(8)));
typedef float    f32x4 __attribute__((ext_vector_type(4)));
typedef unsigned int u32;
typedef u32      u32x2 __attribute__((ext_vector_type(2)));
typedef u32      u32x4 __attribute__((ext_vector_type(4)));

#define MFMA32(a, b, c) __builtin_amdgcn_mfma_f32_16x16x32_f16((a), (b), (c), 0, 0, 0)
// NOTE: legacy K=16 intrinsic has NO underscore before f16 on gfx950
#define MFMA16(a, b, c) __builtin_amdgcn_mfma_f32_16x16x16f16((a), (b), (c), 0, 0, 0)

#define TILES 8   // batch-tiles (of 16) per block; grid = 8192/TILES

__device__ __forceinline__ float leaky(float x) {
    return fmaf(0.4f, __builtin_fabsf(x), 0.6f * x);
}
__device__ __forceinline__ u32 pkrtz(float a, float b) {
    return __builtin_bit_cast(u32, __builtin_amdgcn_cvt_pkrtz(a, b));
}
// leaky(x) == max(x, 0.2x): x>=0 -> x exact; x<0 -> 0.2x (f16 rne). 3 ops/pair.
__device__ __forceinline__ u32 lk_pk2(float a, float b) {
    f16x2 v = __builtin_bit_cast(f16x2, __builtin_amdgcn_cvt_pkrtz(a, b));
    f16x2 s = v * (f16x2){(f16)0.2f, (f16)0.2f};
    f16x2 r = __builtin_elementwise_max(v, s);
    return __builtin_bit_cast(u32, r);
}
__device__ __forceinline__ f16x4 lk_pk4(const f32x4 z) {
    return __builtin_bit_cast(f16x4, (u32x2){ lk_pk2(z[0], z[1]), lk_pk2(z[2], z[3]) });
}
__device__ __forceinline__ f16x4 pk4(const f32x4 z) {
    return __builtin_bit_cast(f16x4, (u32x2){ pkrtz(z[0], z[1]), pkrtz(z[2], z[3]) });
}
__device__ __forceinline__ void st_lk4(void* p, const f32x4 z) {
    *(u32x2*)p = (u32x2){ lk_pk2(z[0], z[1]), lk_pk2(z[2], z[3]) };
}

// ---------------------------------------------------------------------------
// Prepack: f16 MFMA fragments in d_ws (unchanged).
// ---------------------------------------------------------------------------
__global__ void disc_prepack(const float* __restrict__ Wp1, const float* __restrict__ Wp2,
                             const float* __restrict__ Wn1, const float* __restrict__ Wn2,
                             const float* __restrict__ Wl1, const float* __restrict__ Wl2,
                             f16* __restrict__ ws)
{
    int idx = blockIdx.x * 256 + threadIdx.x;
    if (idx >= 84 * 512 + 24 * 256) return;
    float v = 0.0f;
    if (idx < 84 * 512) {
        int f = idx >> 9, r = idx & 511;
        int lane = r >> 3, e = r & 7;
        int m15 = lane & 15, h = lane >> 4;
        if (f < 64) {
            int mt4 = f >> 4, ks4 = f & 15;
            int k = ks4 * 32 + h * 8 + e;
            v = Wl1[k * 64 + mt4 * 16 + m15];
        } else if (f < 72) {
            int q = f - 64, c = q >> 2, mt = q & 3;
            const float* W1 = c ? Wn1 : Wp1;
            v = (lane < 16) ? W1[e * 64 + mt * 16 + m15] : 0.0f;
        } else if (f < 80) {
            int q = f - 72, c = q >> 2, nt2 = (q >> 1) & 1, ks2 = q & 1;
            const float* W2 = c ? Wn2 : Wp2;
            int k = ks2 * 32 + h * 8 + e;
            v = W2[k * 32 + nt2 * 16 + m15];
        } else {
            int q = f - 80, ms5 = q >> 1, ks5 = q & 1;
            int k = ks5 * 32 + h * 8 + e;
            v = Wl2[k * 32 + ms5 * 16 + m15];
        }
    } else {
        int r2 = idx - 84 * 512;
        int f2 = r2 >> 8, rr = r2 & 255;
        int lane = rr >> 2, e = rr & 3;
        int m15 = lane & 15, h = lane >> 4;
        if (f2 < 16) {
            int c = f2 >> 3, kb = (f2 >> 1) & 3, nt = f2 & 1;
            const float* W2 = c ? Wn2 : Wp2;
            v = W2[(kb * 16 + h * 4 + e) * 32 + nt * 16 + m15];
        } else {
            int q = f2 - 16, kb = q >> 1, nt = q & 1;
            v = Wl2[(kb * 16 + h * 4 + e) * 32 + nt * 16 + m15];
        }
    }
    ws[idx] = (f16)v;
}

// ---------------------------------------------------------------------------
// R23: R17 shell + Phase-C weight-traffic halving via 2-tile batching.
//   R22 POST-MORTEM: resident-weight attempt spilled -- (128,2) splits the
//   unified file 128 arch + 128 acc; arch headroom over the ~100 baseline is
//   only ~25 regs. The register-FREE way to cut Phase-C's 512 MB/dispatch of
//   same-address Wl1 L2 reads (the one quantity invariant across all ~54us
//   rounds): amortize each weight load over 2 tiles' x-columns.
//   Structure per pass (4 passes/block): {Phase A+B for tile 2p -> xbuf[0],
//   Phase A+B for tile 2p+1 -> xbuf[1]}, then ONE Phase C reading each
//   weight fragment once and feeding BOTH tiles' acc chains (8 MFMA/k8),
//   then one exchange + dual tail. Wl1 traffic 512->256 MB; weight-load:MFMA
//   ratio halves (also better latency hiding); extra cost = 16 AGPRs + 8KB
//   LDS/wave. Barriers: 4/block.
// LDS: 2 x (Albuf 2048 + xbuf 16384) = 36864 + xchg dbuf 2x8192 = 53248.
// 3 blocks/CU.
// ---------------------------------------------------------------------------
__global__ __launch_bounds__(128, 2) void disc_main(
    const float* __restrict__ adj,
    const float* __restrict__ bp1, const float* __restrict__ bp2,
    const float* __restrict__ bn1, const float* __restrict__ bn2,
    const float* __restrict__ bl1, const float* __restrict__ bl2,
    const float* __restrict__ bl3, const float* __restrict__ Wl3,
    const f16* __restrict__ ws, float* __restrict__ out)
{
    extern __shared__ char smem[];
    const int tid  = threadIdx.x;
    const int lane = tid & 63;
    const int wid  = tid >> 6;      // == channel c this wave owns
    const int h    = lane >> 4;
    const int m15  = lane & 15;
    const int i7   = lane & 7;
    const int r8   = m15 >> 3;

    const f16x8* wsf = (const f16x8*)ws;
    const f16x4* wsq = (const f16x4*)(ws + 84 * 512);   // 16x16x16 B-frags
    const int c = wid;

    // ---- this wave's channel weights/biases (loaded ONCE for all tiles) ---
    const f16x8* w1p = wsf + (64 + c * 4) * 64 + lane;
    f16x8 w1t0 = w1p[0], w1t1 = w1p[64], w1t2 = w1p[128], w1t3 = w1p[192];
    const f16x4* w2p = wsq + (c * 8) * 64 + lane;
    f16x4 w2k00 = w2p[0],   w2k01 = w2p[64];    // kb=0, nt=0/1
    f16x4 w2k10 = w2p[128], w2k11 = w2p[192];   // kb=1
    f16x4 w2k20 = w2p[256], w2k21 = w2p[320];   // kb=2
    f16x4 w2k30 = w2p[384], w2k31 = w2p[448];   // kb=3
    const f32x4* b1p = (const f32x4*)(c ? bn1 : bp1);
    f32x4 b10 = b1p[h], b11 = b1p[4 + h], b12 = b1p[8 + h], b13 = b1p[12 + h];
    const f32x4* b2p = (const f32x4*)(c ? bn2 : bp2);
    f32x4 b20 = b2p[h], b21 = b2p[4 + h];
    f32x4 bl1v0 = ((const f32x4*)bl1)[h],      bl1v1 = ((const f32x4*)bl1)[4 + h];
    f32x4 bl1v2 = ((const f32x4*)bl1)[8 + h],  bl1v3 = ((const f32x4*)bl1)[12 + h];

    // ---- tail weights (wave0 only), hoisted out of the tile loop ----
    f16x4 l200, l201, l210, l211, l220, l221, l230, l231;
    float c0 = 0.0f, c1 = 0.0f, w30 = 0.0f, w31 = 0.0f, bl3s = 0.0f;
    if (wid == 0) {
        const f16x4* wl2p = wsq + 16 * 64 + lane;
        l200 = wl2p[0];   l201 = wl2p[64];
        l210 = wl2p[128]; l211 = wl2p[192];
        l220 = wl2p[256]; l221 = wl2p[320];
        l230 = wl2p[384]; l231 = wl2p[448];
        c0 = bl2[m15]; c1 = bl2[m15 + 16];
        w30 = Wl3[m15]; w31 = Wl3[m15 + 16];
        bl3s = bl3[0];
    }

    char* wbase = smem + wid * 18432;
    char* Albuf = wbase;              // 2048 B
    char* xbuf  = wbase + 2048;       // 16384 B (2 tiles x 8 swizzled 1KB frags)

    const int rxor = ((m15 >> 1) & 3) << 4;
    const bool bsel = ((h >> 1) == r8);    // s3 B-frag block-diag gate
    const int  hlow = h & 1;               // s3 B-frag row-half select
    f32x4 zero4 = {0.0f, 0.0f, 0.0f, 0.0f};
    f16x4 zf4 = {};

    const long blockBase = (long)blockIdx.x * (16 * TILES);

    // ---- prefetch tile 0's raw adj rows into registers ----
    f32x4 c00, c01, c10, c11;
    {
        const f32x4* rp0 = (const f32x4*)(adj + (blockBase + (lane >> 3)) * 128 + c * 64 + (lane & 7) * 8);
        c00 = rp0[0]; c01 = rp0[1];
        const int rid1 = 64 + lane;
        const f32x4* rp1 = (const f32x4*)(adj + (blockBase + (rid1 >> 3)) * 128 + c * 64 + (rid1 & 7) * 8);
        c10 = rp1[0]; c11 = rp1[1];
    }

    #pragma unroll 1
    for (int itp = 0; itp < TILES / 2; ++itp) {
        // ================= Phase A+B for tiles 2*itp and 2*itp+1 ===========
        #pragma unroll 1
        for (int sub = 0; sub < 2; ++sub) {
            const int  itile = itp * 2 + sub;
            const long tb    = blockBase + (long)itile * 16;

            // ---- Phase A: normalize prefetched rows, stage to Albuf ----
            {
                float s = ((c00[0] + c00[1]) + (c00[2] + c00[3])) + ((c01[0] + c01[1]) + (c01[2] + c01[3]));
                float rv = (s > 0.0f) ? __builtin_amdgcn_rcpf(s) : 0.0f;
                u32x4 row = { pkrtz(c00[0] * rv, c00[1] * rv), pkrtz(c00[2] * rv, c00[3] * rv),
                              pkrtz(c01[0] * rv, c01[1] * rv), pkrtz(c01[2] * rv, c01[3] * rv) };
                *(u32x4*)(Albuf + lane * 16) = row;
            }
            {
                float s = ((c10[0] + c10[1]) + (c10[2] + c10[3])) + ((c11[0] + c11[1]) + (c11[2] + c11[3]));
                float rv = (s > 0.0f) ? __builtin_amdgcn_rcpf(s) : 0.0f;
                u32x4 row = { pkrtz(c10[0] * rv, c10[1] * rv), pkrtz(c10[2] * rv, c10[3] * rv),
                              pkrtz(c11[0] * rv, c11[1] * rv), pkrtz(c11[2] * rv, c11[3] * rv) };
                *(u32x4*)(Albuf + (64 + lane) * 16) = row;
            }

            // ---- prefetch next tile's raw rows (hides HBM under compute) --
            if (itile < TILES - 1) {
                const long nb = tb + 16;
                const f32x4* rp0 = (const f32x4*)(adj + (nb + (lane >> 3)) * 128 + c * 64 + (lane & 7) * 8);
                c00 = rp0[0]; c01 = rp0[1];
                const int rid1 = 64 + lane;
                const f32x4* rp1 = (const f32x4*)(adj + (nb + (rid1 >> 3)) * 128 + c * 64 + (rid1 & 7) * 8);
                c10 = rp1[0]; c11 = rp1[1];
            }

            // ---- Phase B: fused GCN, TWO independent t-streams -> xbuf[sub]
            char* xsub = xbuf + (sub << 13);
            #pragma unroll 2
            for (int tp = 0; tp < 4; ++tp) {
                const int ta = tp, tbn = tp + 4;
                f16x8 arow_a = *(const f16x8*)(Albuf + (((2 * ta + r8) * 8 + i7) << 4));
                f16x8 arow_b = *(const f16x8*)(Albuf + (((2 * tbn + r8) * 8 + i7) << 4));

                // s1 both: z^T = W1^T @ A^T + b1 (16x16x32, K=8 pad)
                f32x4 z0a = MFMA32(w1t0, arow_a, b10);
                f32x4 z1a = MFMA32(w1t1, arow_a, b11);
                f32x4 z2a = MFMA32(w1t2, arow_a, b12);
                f32x4 z3a = MFMA32(w1t3, arow_a, b13);
                f32x4 z0b = MFMA32(w1t0, arow_b, b10);
                f32x4 z1b = MFMA32(w1t1, arow_b, b11);
                f32x4 z2b = MFMA32(w1t2, arow_b, b12);
                f32x4 z3b = MFMA32(w1t3, arow_b, b13);

                // s1 -> s2: register pack+leaky (packed f16 math)
                f16x4 xa0 = lk_pk4(z0a), xa1 = lk_pk4(z1a), xa2 = lk_pk4(z2a), xa3 = lk_pk4(z3a);
                f16x4 xb0 = lk_pk4(z0b), xb1 = lk_pk4(z1b), xb2 = lk_pk4(z2b), xb3 = lk_pk4(z3b);

                // s2 both: y_nt = sum_kb x1 @ W2 (4-chain of 16x16x16)
                f32x4 y0a = MFMA16(xa0, w2k00, zero4);
                f32x4 y1a = MFMA16(xa0, w2k01, zero4);
                f32x4 y0b = MFMA16(xb0, w2k00, zero4);
                f32x4 y1b = MFMA16(xb0, w2k01, zero4);
                y0a = MFMA16(xa1, w2k10, y0a);
                y1a = MFMA16(xa1, w2k11, y1a);
                y0b = MFMA16(xb1, w2k10, y0b);
                y1b = MFMA16(xb1, w2k11, y1b);
                y0a = MFMA16(xa2, w2k20, y0a);
                y1a = MFMA16(xa2, w2k21, y1a);
                y0b = MFMA16(xb2, w2k20, y0b);
                y1b = MFMA16(xb2, w2k21, y1b);
                y0a = MFMA16(xa3, w2k30, y0a);
                y1a = MFMA16(xa3, w2k31, y1a);
                y0b = MFMA16(xb3, w2k30, y0b);
                y1b = MFMA16(xb3, w2k31, y1b);

                // s2 -> s3: register pkrtz; B-frag from arow select
                f16x4 pa0 = pk4(y0a), pa1 = pk4(y1a);
                f16x4 pb0 = pk4(y0b), pb1 = pk4(y1b);
                u32x4 ara = __builtin_bit_cast(u32x4, arow_a);
                u32x4 arb = __builtin_bit_cast(u32x4, arow_b);
                f16x4 halfa = __builtin_bit_cast(f16x4,
                    hlow ? (u32x2){ara[2], ara[3]} : (u32x2){ara[0], ara[1]});
                f16x4 halfb = __builtin_bit_cast(f16x4,
                    hlow ? (u32x2){arb[2], arb[3]} : (u32x2){arb[0], arb[1]});
                f16x4 bfra = bsel ? halfa : zf4;
                f16x4 bfrb = bsel ? halfb : zf4;

                // s3 both: x2^T = y^T @ BD_A^T + b2 (16x16x16, K=16 exact)
                f32x4 x2aa = MFMA16(pa0, bfra, b20);
                f32x4 x2ba = MFMA16(pa1, bfra, b21);
                f32x4 x2ab = MFMA16(pb0, bfrb, b20);
                f32x4 x2bb = MFMA16(pb1, bfrb, b21);

                // leaky+pack + swizzled xbuf writes; slot = i7, n = 2t+r8
                const int lga = h >> 1;
                const int lgb = (lga + 2) & 3;
                char* fb = xsub + (i7 << 10);
                {
                    int wx = ((ta & 3) ^ i7) << 4;
                    int basew = ((2 * ta + r8) << 6) + ((h & 1) << 3);
                    st_lk4(fb + ((basew + lga * 16) ^ wx), x2aa);
                    st_lk4(fb + ((basew + lgb * 16) ^ wx), x2ba);
                }
                {
                    int wx = ((tbn & 3) ^ i7) << 4;
                    int basew = ((2 * tbn + r8) << 6) + ((h & 1) << 3);
                    st_lk4(fb + ((basew + lga * 16) ^ wx), x2ab);
                    st_lk4(fb + ((basew + lgb * 16) ^ wx), x2bb);
                }
            }
        }

        // ========== Phase C: one weight pass feeds BOTH tiles' chains ======
        // acc a4x = tile 2*itp, acc e4x = tile 2*itp+1
        f32x4 a40 = wid ? zero4 : bl1v0;
        f32x4 a41 = wid ? zero4 : bl1v1;
        f32x4 a42 = wid ? zero4 : bl1v2;
        f32x4 a43 = wid ? zero4 : bl1v3;
        f32x4 e40 = wid ? zero4 : bl1v0;
        f32x4 e41 = wid ? zero4 : bl1v1;
        f32x4 e42 = wid ? zero4 : bl1v2;
        f32x4 e43 = wid ? zero4 : bl1v3;
        __builtin_amdgcn_s_setprio(1);
        #pragma unroll 4
        for (int k8 = 0; k8 < 8; ++k8) {
            const f16x8* wl = wsf + (c * 8 + k8) * 64 + lane;
            f16x8 w0 = wl[0], w1 = wl[1024], w2 = wl[2048], w3 = wl[3072];
            int xoff = (k8 << 10) + ((m15 * 64 + h * 16) ^ (rxor ^ (k8 << 4)));
            f16x8 xfa = *(const f16x8*)(xbuf + xoff);
            f16x8 xfb = *(const f16x8*)(xbuf + 8192 + xoff);
            a40 = MFMA32(w0, xfa, a40);
            e40 = MFMA32(w0, xfb, e40);
            a41 = MFMA32(w1, xfa, a41);
            e41 = MFMA32(w1, xfb, e41);
            a42 = MFMA32(w2, xfa, a42);
            e42 = MFMA32(w2, xfb, e42);
            a43 = MFMA32(w3, xfa, a43);
            e43 = MFMA32(w3, xfb, e43);
        }
        __builtin_amdgcn_s_setprio(0);

        // ---- cross-wave exchange: dbuf by pass parity, ONE barrier ----
        char* xc = smem + 36864 + ((itp & 1) << 13);
        if (wid == 1) {
            *(f32x4*)(xc +    0 + lane * 16) = a40;
            *(f32x4*)(xc + 1024 + lane * 16) = a41;
            *(f32x4*)(xc + 2048 + lane * 16) = a42;
            *(f32x4*)(xc + 3072 + lane * 16) = a43;
            *(f32x4*)(xc + 4096 + lane * 16) = e40;
            *(f32x4*)(xc + 5120 + lane * 16) = e41;
            *(f32x4*)(xc + 6144 + lane * 16) = e42;
            *(f32x4*)(xc + 7168 + lane * 16) = e43;
        }
        __syncthreads();   // wave1 proceeds into next pass (other xc buffer)

        if (wid == 0) {
            const long ob = blockBase + (long)itp * 32;
            a40 += *(const f32x4*)(xc +    0 + lane * 16);
            a41 += *(const f32x4*)(xc + 1024 + lane * 16);
            a42 += *(const f32x4*)(xc + 2048 + lane * 16);
            a43 += *(const f32x4*)(xc + 3072 + lane * 16);
            e40 += *(const f32x4*)(xc + 4096 + lane * 16);
            e41 += *(const f32x4*)(xc + 5120 + lane * 16);
            e42 += *(const f32x4*)(xc + 6144 + lane * 16);
            e43 += *(const f32x4*)(xc + 7168 + lane * 16);

            // ---- tail for tile A (2*itp) ----
            {
                f16x4 pd0 = lk_pk4(a40), pd1 = lk_pk4(a41);
                f16x4 pd2 = lk_pk4(a42), pd3 = lk_pk4(a43);
                f32x4 a50 = {c0, c0, c0, c0};
                f32x4 a51 = {c1, c1, c1, c1};
                a50 = MFMA16(pd0, l200, a50);
                a51 = MFMA16(pd0, l201, a51);
                a50 = MFMA16(pd1, l210, a50);
                a51 = MFMA16(pd1, l211, a51);
                a50 = MFMA16(pd2, l220, a50);
                a51 = MFMA16(pd2, l221, a51);
                a50 = MFMA16(pd3, l230, a50);
                a51 = MFMA16(pd3, l231, a51);
                #pragma unroll
                for (int r = 0; r < 4; ++r) {
                    float acc = leaky(a50[r]) * w30 + leaky(a51[r]) * w31;
                    acc += __shfl_xor(acc, 1);
                    acc += __shfl_xor(acc, 2);
                    acc += __shfl_xor(acc, 4);
                    acc += __shfl_xor(acc, 8);
                    if (m15 == 0) out[ob + h * 4 + r] = acc + bl3s;
                }
            }
            // ---- tail for tile B (2*itp+1) ----
            {
                f16x4 pd0 = lk_pk4(e40), pd1 = lk_pk4(e41);
                f16x4 pd2 = lk_pk4(e42), pd3 = lk_pk4(e43);
                f32x4 a50 = {c0, c0, c0, c0};
                f32x4 a51 = {c1, c1, c1, c1};
                a50 = MFMA16(pd0, l200, a50);
                a51 = MFMA16(pd0, l201, a51);
                a50 = MFMA16(pd1, l210, a50);
                a51 = MFMA16(pd1, l211, a51);
                a50 = MFMA16(pd2, l220, a50);
                a51 = MFMA16(pd2, l221, a51);
                a50 = MFMA16(pd3, l230, a50);
                a51 = MFMA16(pd3, l231, a51);
                #pragma unroll
                for (int r = 0; r < 4; ++r) {
                    float acc = leaky(a50[r]) * w30 + leaky(a51[r]) * w31;
                    acc += __shfl_xor(acc, 1);
                    acc += __shfl_xor(acc, 2);
                    acc += __shfl_xor(acc, 4);
                    acc += __shfl_xor(acc, 8);
                    if (m15 == 0) out[ob + 16 + h * 4 + r] = acc + bl3s;
                }
            }
        }
    }
}

extern "C" void kernel_launch(void* const* d_in, const int* in_sizes, int n_in,
                              void* d_out, int out_size, void* d_ws, size_t ws_size,
                              hipStream_t stream)
{
    const float* adj  = (const float*)d_in[0];
    const float* Wp1  = (const float*)d_in[1];
    const float* bp1  = (const float*)d_in[2];
    const float* Wp2  = (const float*)d_in[3];
    const float* bp2  = (const float*)d_in[4];
    const float* Wn1  = (const float*)d_in[5];
    const float* bn1  = (const float*)d_in[6];
    const float* Wn2  = (const float*)d_in[7];
    const float* bn2  = (const float*)d_in[8];
    const float* Wl1  = (const float*)d_in[9];
    const float* bl1  = (const float*)d_in[10];
    const float* Wl2  = (const float*)d_in[11];
    const float* bl2  = (const float*)d_in[12];
    const float* Wl3  = (const float*)d_in[13];
    const float* bl3  = (const float*)d_in[14];
    f16* ws = (f16*)d_ws;
    float* out = (float*)d_out;

    // 84*512 + 24*256 = 49152 f16; 192 blocks x 256 threads
    hipLaunchKernelGGL(disc_prepack, dim3(192), dim3(256), 0, stream,
                       Wp1, Wp2, Wn1, Wn2, Wl1, Wl2, ws);

    const int ldsBytes = 53248;  // 2 x 18432 wave areas + 2 x 8192 xchg
    hipFuncSetAttribute(reinterpret_cast<const void*>(disc_main),
                        hipFuncAttributeMaxDynamicSharedMemorySize, ldsBytes);
    hipLaunchKernelGGL(disc_main, dim3(8192 / TILES), dim3(128), ldsBytes, stream,
                       adj, bp1, bp2, bn1, bn2, bl1, bl2, bl3, Wl3, ws, out);
}

// Round 11
// 56.273 us; speedup vs baseline: 1.6388x; 1.2764x over previous
//
#include <hip/hip_runtime.h>

typedef _Float16 f16;
typedef _Float16 f16x2 __attribute__((ext_vector_type(2)));
typedef _Float16 f16x4 __attribute__((ext_vector_type(4)));
typedef _Float16 f16x8 __attribute__((ext_vector_type(8)));
typedef float    f32x4 __attribute__((ext_vector_type(4)));
typedef unsigned int u32;
typedef u32      u32x2 __attribute__((ext_vector_type(2)));
typedef u32      u32x4 __attribute__((ext_vector_type(4)));

#define MFMA32(a, b, c) __builtin_amdgcn_mfma_f32_16x16x32_f16((a), (b), (c), 0, 0, 0)
// NOTE: legacy K=16 intrinsic has NO underscore before f16 on gfx950
#define MFMA16(a, b, c) __builtin_amdgcn_mfma_f32_16x16x16f16((a), (b), (c), 0, 0, 0)

#define TILES 4   // batch-tiles (of 16) per block; grid = 8192/TILES = 2048

__device__ __forceinline__ float leaky(float x) {
    return fmaf(0.4f, __builtin_fabsf(x), 0.6f * x);
}
__device__ __forceinline__ u32 pkrtz(float a, float b) {
    return __builtin_bit_cast(u32, __builtin_amdgcn_cvt_pkrtz(a, b));
}
// leaky(x) == max(x, 0.2x): x>=0 -> x exact; x<0 -> 0.2x (f16 rne). 3 ops/pair.
__device__ __forceinline__ u32 lk_pk2(float a, float b) {
    f16x2 v = __builtin_bit_cast(f16x2, __builtin_amdgcn_cvt_pkrtz(a, b));
    f16x2 s = v * (f16x2){(f16)0.2f, (f16)0.2f};
    f16x2 r = __builtin_elementwise_max(v, s);
    return __builtin_bit_cast(u32, r);
}
__device__ __forceinline__ f16x4 lk_pk4(const f32x4 z) {
    return __builtin_bit_cast(f16x4, (u32x2){ lk_pk2(z[0], z[1]), lk_pk2(z[2], z[3]) });
}
__device__ __forceinline__ f16x4 pk4(const f32x4 z) {
    return __builtin_bit_cast(f16x4, (u32x2){ pkrtz(z[0], z[1]), pkrtz(z[2], z[3]) });
}
__device__ __forceinline__ void st_lk4(void* p, const f32x4 z) {
    *(u32x2*)p = (u32x2){ lk_pk2(z[0], z[1]), lk_pk2(z[2], z[3]) };
}

// ---------------------------------------------------------------------------
// Prepack: f16 MFMA fragments in d_ws (unchanged).
// ---------------------------------------------------------------------------
__global__ void disc_prepack(const float* __restrict__ Wp1, const float* __restrict__ Wp2,
                             const float* __restrict__ Wn1, const float* __restrict__ Wn2,
                             const float* __restrict__ Wl1, const float* __restrict__ Wl2,
                             f16* __restrict__ ws)
{
    int idx = blockIdx.x * 256 + threadIdx.x;
    if (idx >= 84 * 512 + 24 * 256) return;
    float v = 0.0f;
    if (idx < 84 * 512) {
        int f = idx >> 9, r = idx & 511;
        int lane = r >> 3, e = r & 7;
        int m15 = lane & 15, h = lane >> 4;
        if (f < 64) {
            int mt4 = f >> 4, ks4 = f & 15;
            int k = ks4 * 32 + h * 8 + e;
            v = Wl1[k * 64 + mt4 * 16 + m15];
        } else if (f < 72) {
            int q = f - 64, c = q >> 2, mt = q & 3;
            const float* W1 = c ? Wn1 : Wp1;
            v = (lane < 16) ? W1[e * 64 + mt * 16 + m15] : 0.0f;
        } else if (f < 80) {
            int q = f - 72, c = q >> 2, nt2 = (q >> 1) & 1, ks2 = q & 1;
            const float* W2 = c ? Wn2 : Wp2;
            int k = ks2 * 32 + h * 8 + e;
            v = W2[k * 32 + nt2 * 16 + m15];
        } else {
            int q = f - 80, ms5 = q >> 1, ks5 = q & 1;
            int k = ks5 * 32 + h * 8 + e;
            v = Wl2[k * 32 + ms5 * 16 + m15];
        }
    } else {
        int r2 = idx - 84 * 512;
        int f2 = r2 >> 8, rr = r2 & 255;
        int lane = rr >> 2, e = rr & 3;
        int m15 = lane & 15, h = lane >> 4;
        if (f2 < 16) {
            int c = f2 >> 3, kb = (f2 >> 1) & 3, nt = f2 & 1;
            const float* W2 = c ? Wn2 : Wp2;
            v = W2[(kb * 16 + h * 4 + e) * 32 + nt * 16 + m15];
        } else {
            int q = f2 - 16, kb = q >> 1, nt = q & 1;
            v = Wl2[(kb * 16 + h * 4 + e) * 32 + nt * 16 + m15];
        }
    }
    ws[idx] = (f16)v;
}

// ---------------------------------------------------------------------------
// R24: R23's 2-tile-batched Phase C + occupancy restored.
//   R23 POST-MORTEM: batching worked (VGPR 104, no spill) and improved
//   per-wave efficiency 1.4x (wave-residence per tile-channel 5.1 -> 3.6us)
//   but LDS 53248 -> 3 blocks/CU and occ 10% -> net regression. Compose:
//   (1) xchg ALIASED into wave1's dead area (Albuf + xbuf head, dead
//       post-Phase-C; wave1 rewrites it only in next pass's Phase A, after
//       barrier 2 -> race-free write-bar-read-bar, R18-proven pattern).
//       LDS 53248 -> 36864 -> 4 blocks/CU = 8 waves/CU capacity.
//   (2) TILES 8 -> 4 (grid 2048): supply 8 blocks/CU vs cap 4 -> a queued
//       block always ready when one retires (kills the drain tail that
//       halved R23's residency).
//   Cost: 2 barriers/pass (wave0's 8 xchg reads between them), prologue
//   amortized over 2 passes (L2-hot loads, negligible).
//   Arithmetic: 3.6us/tile-ch @ ~6.5 resident -> ~35us; even if efficiency
//   regresses to 5.1 (contention returns) -> ~47us. Both beat 53.6.
// LDS: 2 x (Albuf 2048 + xbuf 16384) = 36864; xchg = wave1 area [18432,26624).
// ---------------------------------------------------------------------------
__global__ __launch_bounds__(128, 2) void disc_main(
    const float* __restrict__ adj,
    const float* __restrict__ bp1, const float* __restrict__ bp2,
    const float* __restrict__ bn1, const float* __restrict__ bn2,
    const float* __restrict__ bl1, const float* __restrict__ bl2,
    const float* __restrict__ bl3, const float* __restrict__ Wl3,
    const f16* __restrict__ ws, float* __restrict__ out)
{
    extern __shared__ char smem[];
    const int tid  = threadIdx.x;
    const int lane = tid & 63;
    const int wid  = tid >> 6;      // == channel c this wave owns
    const int h    = lane >> 4;
    const int m15  = lane & 15;
    const int i7   = lane & 7;
    const int r8   = m15 >> 3;

    const f16x8* wsf = (const f16x8*)ws;
    const f16x4* wsq = (const f16x4*)(ws + 84 * 512);   // 16x16x16 B-frags
    const int c = wid;

    // ---- this wave's channel weights/biases (loaded ONCE for all tiles) ---
    const f16x8* w1p = wsf + (64 + c * 4) * 64 + lane;
    f16x8 w1t0 = w1p[0], w1t1 = w1p[64], w1t2 = w1p[128], w1t3 = w1p[192];
    const f16x4* w2p = wsq + (c * 8) * 64 + lane;
    f16x4 w2k00 = w2p[0],   w2k01 = w2p[64];    // kb=0, nt=0/1
    f16x4 w2k10 = w2p[128], w2k11 = w2p[192];   // kb=1
    f16x4 w2k20 = w2p[256], w2k21 = w2p[320];   // kb=2
    f16x4 w2k30 = w2p[384], w2k31 = w2p[448];   // kb=3
    const f32x4* b1p = (const f32x4*)(c ? bn1 : bp1);
    f32x4 b10 = b1p[h], b11 = b1p[4 + h], b12 = b1p[8 + h], b13 = b1p[12 + h];
    const f32x4* b2p = (const f32x4*)(c ? bn2 : bp2);
    f32x4 b20 = b2p[h], b21 = b2p[4 + h];
    f32x4 bl1v0 = ((const f32x4*)bl1)[h],      bl1v1 = ((const f32x4*)bl1)[4 + h];
    f32x4 bl1v2 = ((const f32x4*)bl1)[8 + h],  bl1v3 = ((const f32x4*)bl1)[12 + h];

    // ---- tail weights (wave0 only), hoisted out of the tile loop ----
    f16x4 l200, l201, l210, l211, l220, l221, l230, l231;
    float c0 = 0.0f, c1 = 0.0f, w30 = 0.0f, w31 = 0.0f, bl3s = 0.0f;
    if (wid == 0) {
        const f16x4* wl2p = wsq + 16 * 64 + lane;
        l200 = wl2p[0];   l201 = wl2p[64];
        l210 = wl2p[128]; l211 = wl2p[192];
        l220 = wl2p[256]; l221 = wl2p[320];
        l230 = wl2p[384]; l231 = wl2p[448];
        c0 = bl2[m15]; c1 = bl2[m15 + 16];
        w30 = Wl3[m15]; w31 = Wl3[m15 + 16];
        bl3s = bl3[0];
    }

    char* wbase = smem + wid * 18432;
    char* Albuf = wbase;              // 2048 B
    char* xbuf  = wbase + 2048;       // 16384 B (2 tiles x 8 swizzled 1KB frags)
    char* xchg  = smem + 18432;       // 8 KB aliased over wave1's Albuf+xbuf head
                                      // (dead post-C; rewritten only after bar 2)

    const int rxor = ((m15 >> 1) & 3) << 4;
    const bool bsel = ((h >> 1) == r8);    // s3 B-frag block-diag gate
    const int  hlow = h & 1;               // s3 B-frag row-half select
    f32x4 zero4 = {0.0f, 0.0f, 0.0f, 0.0f};
    f16x4 zf4 = {};

    const long blockBase = (long)blockIdx.x * (16 * TILES);

    // ---- prefetch tile 0's raw adj rows into registers ----
    f32x4 c00, c01, c10, c11;
    {
        const f32x4* rp0 = (const f32x4*)(adj + (blockBase + (lane >> 3)) * 128 + c * 64 + (lane & 7) * 8);
        c00 = rp0[0]; c01 = rp0[1];
        const int rid1 = 64 + lane;
        const f32x4* rp1 = (const f32x4*)(adj + (blockBase + (rid1 >> 3)) * 128 + c * 64 + (rid1 & 7) * 8);
        c10 = rp1[0]; c11 = rp1[1];
    }

    #pragma unroll 1
    for (int itp = 0; itp < TILES / 2; ++itp) {
        // ================= Phase A+B for tiles 2*itp and 2*itp+1 ===========
        #pragma unroll 1
        for (int sub = 0; sub < 2; ++sub) {
            const int  itile = itp * 2 + sub;
            const long tb    = blockBase + (long)itile * 16;

            // ---- Phase A: normalize prefetched rows, stage to Albuf ----
            {
                float s = ((c00[0] + c00[1]) + (c00[2] + c00[3])) + ((c01[0] + c01[1]) + (c01[2] + c01[3]));
                float rv = (s > 0.0f) ? __builtin_amdgcn_rcpf(s) : 0.0f;
                u32x4 row = { pkrtz(c00[0] * rv, c00[1] * rv), pkrtz(c00[2] * rv, c00[3] * rv),
                              pkrtz(c01[0] * rv, c01[1] * rv), pkrtz(c01[2] * rv, c01[3] * rv) };
                *(u32x4*)(Albuf + lane * 16) = row;
            }
            {
                float s = ((c10[0] + c10[1]) + (c10[2] + c10[3])) + ((c11[0] + c11[1]) + (c11[2] + c11[3]));
                float rv = (s > 0.0f) ? __builtin_amdgcn_rcpf(s) : 0.0f;
                u32x4 row = { pkrtz(c10[0] * rv, c10[1] * rv), pkrtz(c10[2] * rv, c10[3] * rv),
                              pkrtz(c11[0] * rv, c11[1] * rv), pkrtz(c11[2] * rv, c11[3] * rv) };
                *(u32x4*)(Albuf + (64 + lane) * 16) = row;
            }

            // ---- prefetch next tile's raw rows (hides HBM under compute) --
            if (itile < TILES - 1) {
                const long nb = tb + 16;
                const f32x4* rp0 = (const f32x4*)(adj + (nb + (lane >> 3)) * 128 + c * 64 + (lane & 7) * 8);
                c00 = rp0[0]; c01 = rp0[1];
                const int rid1 = 64 + lane;
                const f32x4* rp1 = (const f32x4*)(adj + (nb + (rid1 >> 3)) * 128 + c * 64 + (rid1 & 7) * 8);
                c10 = rp1[0]; c11 = rp1[1];
            }

            // ---- Phase B: fused GCN, TWO independent t-streams -> xbuf[sub]
            char* xsub = xbuf + (sub << 13);
            #pragma unroll 2
            for (int tp = 0; tp < 4; ++tp) {
                const int ta = tp, tbn = tp + 4;
                f16x8 arow_a = *(const f16x8*)(Albuf + (((2 * ta + r8) * 8 + i7) << 4));
                f16x8 arow_b = *(const f16x8*)(Albuf + (((2 * tbn + r8) * 8 + i7) << 4));

                // s1 both: z^T = W1^T @ A^T + b1 (16x16x32, K=8 pad)
                f32x4 z0a = MFMA32(w1t0, arow_a, b10);
                f32x4 z1a = MFMA32(w1t1, arow_a, b11);
                f32x4 z2a = MFMA32(w1t2, arow_a, b12);
                f32x4 z3a = MFMA32(w1t3, arow_a, b13);
                f32x4 z0b = MFMA32(w1t0, arow_b, b10);
                f32x4 z1b = MFMA32(w1t1, arow_b, b11);
                f32x4 z2b = MFMA32(w1t2, arow_b, b12);
                f32x4 z3b = MFMA32(w1t3, arow_b, b13);

                // s1 -> s2: register pack+leaky (packed f16 math)
                f16x4 xa0 = lk_pk4(z0a), xa1 = lk_pk4(z1a), xa2 = lk_pk4(z2a), xa3 = lk_pk4(z3a);
                f16x4 xb0 = lk_pk4(z0b), xb1 = lk_pk4(z1b), xb2 = lk_pk4(z2b), xb3 = lk_pk4(z3b);

                // s2 both: y_nt = sum_kb x1 @ W2 (4-chain of 16x16x16)
                f32x4 y0a = MFMA16(xa0, w2k00, zero4);
                f32x4 y1a = MFMA16(xa0, w2k01, zero4);
                f32x4 y0b = MFMA16(xb0, w2k00, zero4);
                f32x4 y1b = MFMA16(xb0, w2k01, zero4);
                y0a = MFMA16(xa1, w2k10, y0a);
                y1a = MFMA16(xa1, w2k11, y1a);
                y0b = MFMA16(xb1, w2k10, y0b);
                y1b = MFMA16(xb1, w2k11, y1b);
                y0a = MFMA16(xa2, w2k20, y0a);
                y1a = MFMA16(xa2, w2k21, y1a);
                y0b = MFMA16(xb2, w2k20, y0b);
                y1b = MFMA16(xb2, w2k21, y1b);
                y0a = MFMA16(xa3, w2k30, y0a);
                y1a = MFMA16(xa3, w2k31, y1a);
                y0b = MFMA16(xb3, w2k30, y0b);
                y1b = MFMA16(xb3, w2k31, y1b);

                // s2 -> s3: register pkrtz; B-frag from arow select
                f16x4 pa0 = pk4(y0a), pa1 = pk4(y1a);
                f16x4 pb0 = pk4(y0b), pb1 = pk4(y1b);
                u32x4 ara = __builtin_bit_cast(u32x4, arow_a);
                u32x4 arb = __builtin_bit_cast(u32x4, arow_b);
                f16x4 halfa = __builtin_bit_cast(f16x4,
                    hlow ? (u32x2){ara[2], ara[3]} : (u32x2){ara[0], ara[1]});
                f16x4 halfb = __builtin_bit_cast(f16x4,
                    hlow ? (u32x2){arb[2], arb[3]} : (u32x2){arb[0], arb[1]});
                f16x4 bfra = bsel ? halfa : zf4;
                f16x4 bfrb = bsel ? halfb : zf4;

                // s3 both: x2^T = y^T @ BD_A^T + b2 (16x16x16, K=16 exact)
                f32x4 x2aa = MFMA16(pa0, bfra, b20);
                f32x4 x2ba = MFMA16(pa1, bfra, b21);
                f32x4 x2ab = MFMA16(pb0, bfrb, b20);
                f32x4 x2bb = MFMA16(pb1, bfrb, b21);

                // leaky+pack + swizzled xbuf writes; slot = i7, n = 2t+r8
                const int lga = h >> 1;
                const int lgb = (lga + 2) & 3;
                char* fb = xsub + (i7 << 10);
                {
                    int wx = ((ta & 3) ^ i7) << 4;
                    int basew = ((2 * ta + r8) << 6) + ((h & 1) << 3);
                    st_lk4(fb + ((basew + lga * 16) ^ wx), x2aa);
                    st_lk4(fb + ((basew + lgb * 16) ^ wx), x2ba);
                }
                {
                    int wx = ((tbn & 3) ^ i7) << 4;
                    int basew = ((2 * tbn + r8) << 6) + ((h & 1) << 3);
                    st_lk4(fb + ((basew + lga * 16) ^ wx), x2ab);
                    st_lk4(fb + ((basew + lgb * 16) ^ wx), x2bb);
                }
            }
        }

        // ========== Phase C: one weight pass feeds BOTH tiles' chains ======
        // acc a4x = tile 2*itp, acc e4x = tile 2*itp+1
        f32x4 a40 = wid ? zero4 : bl1v0;
        f32x4 a41 = wid ? zero4 : bl1v1;
        f32x4 a42 = wid ? zero4 : bl1v2;
        f32x4 a43 = wid ? zero4 : bl1v3;
        f32x4 e40 = wid ? zero4 : bl1v0;
        f32x4 e41 = wid ? zero4 : bl1v1;
        f32x4 e42 = wid ? zero4 : bl1v2;
        f32x4 e43 = wid ? zero4 : bl1v3;
        __builtin_amdgcn_s_setprio(1);
        #pragma unroll 4
        for (int k8 = 0; k8 < 8; ++k8) {
            const f16x8* wl = wsf + (c * 8 + k8) * 64 + lane;
            f16x8 w0 = wl[0], w1 = wl[1024], w2 = wl[2048], w3 = wl[3072];
            int xoff = (k8 << 10) + ((m15 * 64 + h * 16) ^ (rxor ^ (k8 << 4)));
            f16x8 xfa = *(const f16x8*)(xbuf + xoff);
            f16x8 xfb = *(const f16x8*)(xbuf + 8192 + xoff);
            a40 = MFMA32(w0, xfa, a40);
            e40 = MFMA32(w0, xfb, e40);
            a41 = MFMA32(w1, xfa, a41);
            e41 = MFMA32(w1, xfb, e41);
            a42 = MFMA32(w2, xfa, a42);
            e42 = MFMA32(w2, xfb, e42);
            a43 = MFMA32(w3, xfa, a43);
            e43 = MFMA32(w3, xfb, e43);
        }
        __builtin_amdgcn_s_setprio(0);

        // ---- cross-wave exchange: aliased xchg, write-bar-read-bar ----
        if (wid == 1) {
            *(f32x4*)(xchg +    0 + lane * 16) = a40;
            *(f32x4*)(xchg + 1024 + lane * 16) = a41;
            *(f32x4*)(xchg + 2048 + lane * 16) = a42;
            *(f32x4*)(xchg + 3072 + lane * 16) = a43;
            *(f32x4*)(xchg + 4096 + lane * 16) = e40;
            *(f32x4*)(xchg + 5120 + lane * 16) = e41;
            *(f32x4*)(xchg + 6144 + lane * 16) = e42;
            *(f32x4*)(xchg + 7168 + lane * 16) = e43;
        }
        __syncthreads();
        f32x4 p0, p1, p2, p3, q0, q1, q2, q3;
        if (wid == 0) {
            p0 = *(const f32x4*)(xchg +    0 + lane * 16);
            p1 = *(const f32x4*)(xchg + 1024 + lane * 16);
            p2 = *(const f32x4*)(xchg + 2048 + lane * 16);
            p3 = *(const f32x4*)(xchg + 3072 + lane * 16);
            q0 = *(const f32x4*)(xchg + 4096 + lane * 16);
            q1 = *(const f32x4*)(xchg + 5120 + lane * 16);
            q2 = *(const f32x4*)(xchg + 6144 + lane * 16);
            q3 = *(const f32x4*)(xchg + 7168 + lane * 16);
        }
        __syncthreads();   // wave1 may now rewrite its area (next pass A/B)

        if (wid == 0) {
            const long ob = blockBase + (long)itp * 32;
            a40 += p0; a41 += p1; a42 += p2; a43 += p3;
            e40 += q0; e41 += q1; e42 += q2; e43 += q3;

            // ---- tail for tile A (2*itp) ----
            {
                f16x4 pd0 = lk_pk4(a40), pd1 = lk_pk4(a41);
                f16x4 pd2 = lk_pk4(a42), pd3 = lk_pk4(a43);
                f32x4 a50 = {c0, c0, c0, c0};
                f32x4 a51 = {c1, c1, c1, c1};
                a50 = MFMA16(pd0, l200, a50);
                a51 = MFMA16(pd0, l201, a51);
                a50 = MFMA16(pd1, l210, a50);
                a51 = MFMA16(pd1, l211, a51);
                a50 = MFMA16(pd2, l220, a50);
                a51 = MFMA16(pd2, l221, a51);
                a50 = MFMA16(pd3, l230, a50);
                a51 = MFMA16(pd3, l231, a51);
                #pragma unroll
                for (int r = 0; r < 4; ++r) {
                    float acc = leaky(a50[r]) * w30 + leaky(a51[r]) * w31;
                    acc += __shfl_xor(acc, 1);
                    acc += __shfl_xor(acc, 2);
                    acc += __shfl_xor(acc, 4);
                    acc += __shfl_xor(acc, 8);
                    if (m15 == 0) out[ob + h * 4 + r] = acc + bl3s;
                }
            }
            // ---- tail for tile B (2*itp+1) ----
            {
                f16x4 pd0 = lk_pk4(e40), pd1 = lk_pk4(e41);
                f16x4 pd2 = lk_pk4(e42), pd3 = lk_pk4(e43);
                f32x4 a50 = {c0, c0, c0, c0};
                f32x4 a51 = {c1, c1, c1, c1};
                a50 = MFMA16(pd0, l200, a50);
                a51 = MFMA16(pd0, l201, a51);
                a50 = MFMA16(pd1, l210, a50);
                a51 = MFMA16(pd1, l211, a51);
                a50 = MFMA16(pd2, l220, a50);
                a51 = MFMA16(pd2, l221, a51);
                a50 = MFMA16(pd3, l230, a50);
                a51 = MFMA16(pd3, l231, a51);
                #pragma unroll
                for (int r = 0; r < 4; ++r) {
                    float acc = leaky(a50[r]) * w30 + leaky(a51[r]) * w31;
                    acc += __shfl_xor(acc, 1);
                    acc += __shfl_xor(acc, 2);
                    acc += __shfl_xor(acc, 4);
                    acc += __shfl_xor(acc, 8);
                    if (m15 == 0) out[ob + 16 + h * 4 + r] = acc + bl3s;
                }
            }
        }
    }
}

extern "C" void kernel_launch(void* const* d_in, const int* in_sizes, int n_in,
                              void* d_out, int out_size, void* d_ws, size_t ws_size,
                              hipStream_t stream)
{
    const float* adj  = (const float*)d_in[0];
    const float* Wp1  = (const float*)d_in[1];
    const float* bp1  = (const float*)d_in[2];
    const float* Wp2  = (const float*)d_in[3];
    const float* bp2  = (const float*)d_in[4];
    const float* Wn1  = (const float*)d_in[5];
    const float* bn1  = (const float*)d_in[6];
    const float* Wn2  = (const float*)d_in[7];
    const float* bn2  = (const float*)d_in[8];
    const float* Wl1  = (const float*)d_in[9];
    const float* bl1  = (const float*)d_in[10];
    const float* Wl2  = (const float*)d_in[11];
    const float* bl2  = (const float*)d_in[12];
    const float* Wl3  = (const float*)d_in[13];
    const float* bl3  = (const float*)d_in[14];
    f16* ws = (f16*)d_ws;
    float* out = (float*)d_out;

    // 84*512 + 24*256 = 49152 f16; 192 blocks x 256 threads
    hipLaunchKernelGGL(disc_prepack, dim3(192), dim3(256), 0, stream,
                       Wp1, Wp2, Wn1, Wn2, Wl1, Wl2, ws);

    const int ldsBytes = 36864;  // 2 x 18432 wave areas; xchg aliased in wave1's
    hipFuncSetAttribute(reinterpret_cast<const void*>(disc_main),
                        hipFuncAttributeMaxDynamicSharedMemorySize, ldsBytes);
    hipLaunchKernelGGL(disc_main, dim3(8192 / TILES), dim3(128), ldsBytes, stream,
                       adj, bp1, bp2, bn1, bn2, bl1, bl2, bl3, Wl3, ws, out);
}